// Round 8
// baseline (435.575 us; speedup 1.0000x reference)
//
#include <hip/hip_runtime.h>
#include <hip/hip_bf16.h>
#include <math.h>

typedef __bf16 bf16;
typedef bf16 bf16x8 __attribute__((ext_vector_type(8)));
typedef bf16 bf16x4 __attribute__((ext_vector_type(4)));
typedef float f32x4 __attribute__((ext_vector_type(4)));

#define HDIM 1024
#define NHEADS 8
#define HD 128
#define MD1 256
#define MD2 128
#define LNEPS 1e-5f

__device__ __forceinline__ f32x4 mfma16(bf16x8 a, bf16x8 b, f32x4 c) {
  return __builtin_amdgcn_mfma_f32_16x16x32_bf16(a, b, c, 0, 0, 0);
}

__device__ __forceinline__ void gload_lds16(const bf16* g, bf16* l) {
  __builtin_amdgcn_global_load_lds(
      (const __attribute__((address_space(1))) void*)g,
      (__attribute__((address_space(3))) void*)l, 16, 0, 0);
}

// ---------------- fused prep: x=hs+pos cast, + all weight converts ----------------
__global__ void k_prep_all(
    const float* __restrict__ hs, const float* __restrict__ pos,
    bf16* __restrict__ xbf, int SH, int nprep,
    const float* __restrict__ s0, bf16* __restrict__ d0, int n0,
    const float* __restrict__ s1, bf16* __restrict__ d1, int n1,
    const float* __restrict__ s2, bf16* __restrict__ d2, int n2,
    const float* __restrict__ s3, bf16* __restrict__ d3, int n3) {
  int i = (blockIdx.x * blockDim.x + threadIdx.x) * 4;
  if (i < nprep) {
    float4 a = *(const float4*)(hs + i);
    float4 p = *(const float4*)(pos + (i % SH));
    bf16x4 o;
    o[0] = (bf16)(a.x + p.x); o[1] = (bf16)(a.y + p.y);
    o[2] = (bf16)(a.z + p.z); o[3] = (bf16)(a.w + p.w);
    *(bf16x4*)(xbf + i) = o;
    return;
  }
  int j = i - nprep;
  const float* s; bf16* d;
  if (j < n0)                { s = s0 + j; d = d0 + j; }
  else if (j < n0 + n1)      { s = s1 + (j - n0); d = d1 + (j - n0); }
  else if (j < n0 + n1 + n2) { s = s2 + (j - n0 - n1); d = d2 + (j - n0 - n1); }
  else                       { s = s3 + (j - n0 - n1 - n2); d = d3 + (j - n0 - n1 - n2); }
  float4 v = *(const float4*)s;
  bf16x4 o;
  o[0] = (bf16)v.x; o[1] = (bf16)v.y; o[2] = (bf16)v.z; o[3] = (bf16)v.w;
  *(bf16x4*)d = o;
}

// ---------------- 128x128-tile MFMA GEMM: C = A @ Bw^T + bias ----------------
template<bool OUT_BF>
__global__ __launch_bounds__(256) void k_gemm128(
    const bf16* __restrict__ A, const bf16* __restrict__ Bw,
    const float* __restrict__ bias, void* __restrict__ out,
    int N, int K) {
  __shared__ bf16 As[128 * 32];
  __shared__ bf16 Bs[128 * 32];
  const int tid = threadIdx.x;
  const int w = tid >> 6, lane = tid & 63;
  const int quad = lane >> 4, l16 = lane & 15;
  const int wm = w & 1, wn = w >> 1;
  const int tm = blockIdx.x * 128, tn = blockIdx.y * 128;

  const int r0 = tid >> 2;
  const int f0 = (r0 ^ (r0 >> 2)) & 3;
  const int f1 = ((r0 + 64) ^ ((r0 + 64) >> 2)) & 3;
  const int c0 = (((tid & 3) ^ f0) * 8);
  const int c1 = (((tid & 3) ^ f1) * 8);
  const bf16* a0 = A + (size_t)(tm + r0) * K + c0;
  const bf16* a1 = A + (size_t)(tm + r0 + 64) * K + c1;
  const bf16* b0 = Bw + (size_t)(tn + r0) * K + c0;
  const bf16* b1 = Bw + (size_t)(tn + r0 + 64) * K + c1;
  bf16* lA = As + (size_t)tid * 8;
  bf16* lB = Bs + (size_t)tid * 8;

  f32x4 acc[4][4] = {};
  for (int k0 = 0; k0 < K; k0 += 32) {
    gload_lds16(a0 + k0, lA);
    gload_lds16(a1 + k0, lA + 2048);
    gload_lds16(b0 + k0, lB);
    gload_lds16(b1 + k0, lB + 2048);
    __syncthreads();
    bf16x8 af[4], bfr[4];
#pragma unroll
    for (int mt = 0; mt < 4; ++mt) {
      const int r = wm * 64 + mt * 16 + l16;
      af[mt] = *(const bf16x8*)&As[r * 32 + ((quad ^ ((r ^ (r >> 2)) & 3)) << 3)];
    }
#pragma unroll
    for (int nt = 0; nt < 4; ++nt) {
      const int r = wn * 64 + nt * 16 + l16;
      bfr[nt] = *(const bf16x8*)&Bs[r * 32 + ((quad ^ ((r ^ (r >> 2)) & 3)) << 3)];
    }
#pragma unroll
    for (int mt = 0; mt < 4; ++mt)
#pragma unroll
      for (int nt = 0; nt < 4; ++nt)
        acc[mt][nt] = mfma16(af[mt], bfr[nt], acc[mt][nt]);
    __syncthreads();
  }

#pragma unroll
  for (int nt = 0; nt < 4; ++nt) {
    const int col = tn + wn * 64 + nt * 16 + l16;
    const float bv = bias ? bias[col] : 0.f;
#pragma unroll
    for (int mt = 0; mt < 4; ++mt) {
#pragma unroll
      for (int i = 0; i < 4; ++i) {
        const int row = tm + wm * 64 + mt * 16 + quad * 4 + i;
        const float v = acc[mt][nt][i] + bv;
        if (OUT_BF) ((bf16*)out)[(size_t)row * N + col] = (bf16)v;
        else        ((float*)out)[(size_t)row * N + col] = v;
      }
    }
  }
}

// ---------------- QKV GEMM: epilogue splits Q / K row-major, V transposed ----------
__global__ __launch_bounds__(256) void k_gemm_qkv(
    const bf16* __restrict__ A, const bf16* __restrict__ Bw,
    const float* __restrict__ bias, bf16* __restrict__ Qo,
    bf16* __restrict__ Ko, bf16* __restrict__ VTo, int S, int K) {
  __shared__ bf16 As[128 * 32];
  __shared__ bf16 Bs[128 * 32];
  const int tid = threadIdx.x;
  const int w = tid >> 6, lane = tid & 63;
  const int quad = lane >> 4, l16 = lane & 15;
  const int wm = w & 1, wn = w >> 1;
  const int tm = blockIdx.x * 128, tn = blockIdx.y * 128;

  const int r0 = tid >> 2;
  const int f0 = (r0 ^ (r0 >> 2)) & 3;
  const int f1 = ((r0 + 64) ^ ((r0 + 64) >> 2)) & 3;
  const int c0 = (((tid & 3) ^ f0) * 8);
  const int c1 = (((tid & 3) ^ f1) * 8);
  const bf16* a0 = A + (size_t)(tm + r0) * K + c0;
  const bf16* a1 = A + (size_t)(tm + r0 + 64) * K + c1;
  const bf16* b0 = Bw + (size_t)(tn + r0) * K + c0;
  const bf16* b1 = Bw + (size_t)(tn + r0 + 64) * K + c1;
  bf16* lA = As + (size_t)tid * 8;
  bf16* lB = Bs + (size_t)tid * 8;

  f32x4 acc[4][4] = {};
  for (int k0 = 0; k0 < K; k0 += 32) {
    gload_lds16(a0 + k0, lA);
    gload_lds16(a1 + k0, lA + 2048);
    gload_lds16(b0 + k0, lB);
    gload_lds16(b1 + k0, lB + 2048);
    __syncthreads();
    bf16x8 af[4], bfr[4];
#pragma unroll
    for (int mt = 0; mt < 4; ++mt) {
      const int r = wm * 64 + mt * 16 + l16;
      af[mt] = *(const bf16x8*)&As[r * 32 + ((quad ^ ((r ^ (r >> 2)) & 3)) << 3)];
    }
#pragma unroll
    for (int nt = 0; nt < 4; ++nt) {
      const int r = wn * 64 + nt * 16 + l16;
      bfr[nt] = *(const bf16x8*)&Bs[r * 32 + ((quad ^ ((r ^ (r >> 2)) & 3)) << 3)];
    }
#pragma unroll
    for (int mt = 0; mt < 4; ++mt)
#pragma unroll
      for (int nt = 0; nt < 4; ++nt)
        acc[mt][nt] = mfma16(af[mt], bfr[nt], acc[mt][nt]);
    __syncthreads();
  }

  const int region = tn >> 10;            // 0:Q 1:K 2:V
  const int btile = tm / S, s0 = tm % S;
#pragma unroll
  for (int nt = 0; nt < 4; ++nt) {
    const int col = tn + wn * 64 + nt * 16 + l16;
    const float bv = bias[col];
#pragma unroll
    for (int mt = 0; mt < 4; ++mt) {
      if (region == 2) {
        const int d = col - 2048, hh = d >> 7, dd = d & 127;
        const int sb = s0 + wm * 64 + mt * 16 + quad * 4;
        bf16x4 o4;
#pragma unroll
        for (int i = 0; i < 4; ++i) o4[i] = (bf16)(acc[mt][nt][i] + bv);
        *(bf16x4*)&VTo[((size_t)(btile * NHEADS + hh) * HD + dd) * S + sb] = o4;
      } else {
        bf16* dst = (region == 0) ? Qo : Ko;
        const int cc = (region == 0) ? col : col - 1024;
#pragma unroll
        for (int i = 0; i < 4; ++i) {
          const int row = tm + wm * 64 + mt * 16 + quad * 4 + i;
          dst[(size_t)row * HDIM + cc] = (bf16)(acc[mt][nt][i] + bv);
        }
      }
    }
  }
}

// ---------------- flash attention, split-K over keys (fixed-max softmax) --------
// grid (S/128, B*NHEADS, 2). Each split writes UNNORMALIZED o (bf16) + lsum (f32).
__global__ __launch_bounds__(256) void k_flash(
    const bf16* __restrict__ Qg, const bf16* __restrict__ Kg,
    const bf16* __restrict__ VTg, const int* __restrict__ mask,
    bf16* __restrict__ opart, float* __restrict__ lpart, int S, int Mtot) {
  __shared__ bf16 Ks[64][136];
  __shared__ bf16 Vt[128 * 64];
  __shared__ bf16 Ps[8 * 1024];
  __shared__ float biass[64];
  const int tid = threadIdx.x, w = tid >> 6, lane = tid & 63;
  const int quad = lane >> 4, l16 = lane & 15;
  const int bh = blockIdx.y, b = bh / NHEADS, h = bh % NHEADS;
  const int split = blockIdx.z;
  const int klo = split * (S >> 1), khi = klo + (S >> 1);
  const int q0 = blockIdx.x * 128 + w * 32;
  const size_t bS = (size_t)b * S;
  const bf16* Qb = Qg + bS * HDIM + h * HD;
  const bf16* Kb = Kg + bS * HDIM + h * HD;
  const bf16* Vb = VTg + (size_t)bh * HD * S;
  const int* mrow = mask + bS;
  bf16* op = opart + (size_t)split * Mtot * HDIM;
  float* lp = lpart + (size_t)split * Mtot * NHEADS;

  bf16x8 qf[2][4];
#pragma unroll
  for (int qt = 0; qt < 2; ++qt)
#pragma unroll
    for (int s = 0; s < 4; ++s)
      qf[qt][s] = *(const bf16x8*)(Qb + (size_t)(q0 + qt * 16 + l16) * HDIM + s * 32 + quad * 8);

  float lsum[2][4] = {};
  f32x4 o[2][8] = {};
  const float scale2 = 0.08838834764831845f * 1.4426950408889634f;

  bf16x8 kreg[4], vreg[4];
  int mreg = (tid < 64) ? mrow[klo + tid] : 0;
#pragma unroll
  for (int it = 0; it < 4; ++it) {
    const int cid = tid + it * 256;
    kreg[it] = *(const bf16x8*)(Kb + (size_t)(klo + (cid >> 4)) * HDIM + (cid & 15) * 8);
    vreg[it] = *(const bf16x8*)(Vb + (size_t)(cid >> 3) * S + klo + (cid & 7) * 8);
  }

  for (int key0 = klo; key0 < khi; key0 += 64) {
    __syncthreads();
#pragma unroll
    for (int it = 0; it < 4; ++it) {
      const int cid = tid + it * 256;
      *(bf16x8*)&Ks[cid >> 4][(cid & 15) * 8] = kreg[it];
      const int vd = cid >> 3, vkb = cid & 7;
      *(bf16x8*)&Vt[vd * 64 + ((vkb ^ (vd & 7)) << 3)] = vreg[it];
    }
    if (tid < 64) biass[tid] = mreg ? 0.f : -1e9f;
    __syncthreads();
    const int key0n = (key0 + 64 < khi) ? key0 + 64 : key0;
    if (tid < 64) mreg = mrow[key0n + tid];
#pragma unroll
    for (int it = 0; it < 4; ++it) {
      const int cid = tid + it * 256;
      kreg[it] = *(const bf16x8*)(Kb + (size_t)(key0n + (cid >> 4)) * HDIM + (cid & 15) * 8);
      vreg[it] = *(const bf16x8*)(Vb + (size_t)(cid >> 3) * S + key0n + (cid & 7) * 8);
    }
    f32x4 s4[2][4] = {};
#pragma unroll
    for (int g = 0; g < 4; ++g)
#pragma unroll
      for (int s = 0; s < 4; ++s) {
        bf16x8 kf = *(const bf16x8*)&Ks[g * 16 + l16][s * 32 + quad * 8];
        s4[0][g] = mfma16(qf[0][s], kf, s4[0][g]);
        s4[1][g] = mfma16(qf[1][s], kf, s4[1][g]);
      }
#pragma unroll
    for (int qt = 0; qt < 2; ++qt) {
      const int base = (w * 2 + qt) * 1024;
#pragma unroll
      for (int g = 0; g < 4; ++g) {
        const float bias = biass[g * 16 + l16];
        const int kb2 = 2 * g + (l16 >> 3), klo2 = l16 & 7;
#pragma unroll
        for (int i = 0; i < 4; ++i) {
          const float p = exp2f(fmaf(s4[qt][g][i], scale2, bias));
          lsum[qt][i] += p;
          const int r = quad * 4 + i, fr = (r ^ (r >> 3)) & 7;
          Ps[base + r * 64 + ((kb2 ^ fr) << 3) + klo2] = (bf16)p;
        }
      }
    }
    const int fl = (l16 ^ (l16 >> 3)) & 7;
#pragma unroll
    for (int hh = 0; hh < 2; ++hh) {
      const int kb = hh * 4 + quad;
      bf16x8 pf0 = *(const bf16x8*)&Ps[(w * 2) * 1024 + l16 * 64 + ((kb ^ fl) << 3)];
      bf16x8 pf1 = *(const bf16x8*)&Ps[(w * 2 + 1) * 1024 + l16 * 64 + ((kb ^ fl) << 3)];
#pragma unroll
      for (int dg = 0; dg < 8; ++dg) {
        const int d = dg * 16 + l16;
        bf16x8 vf = *(const bf16x8*)&Vt[d * 64 + ((kb ^ (d & 7)) << 3)];
        o[0][dg] = mfma16(pf0, vf, o[0][dg]);
        o[1][dg] = mfma16(pf1, vf, o[1][dg]);
      }
    }
  }

#pragma unroll
  for (int qt = 0; qt < 2; ++qt)
#pragma unroll
    for (int i = 0; i < 4; ++i) {
      float ls = lsum[qt][i];
#pragma unroll
      for (int off = 1; off < 16; off <<= 1) ls += __shfl_xor(ls, off);
      const int row = q0 + qt * 16 + quad * 4 + i;
      if (l16 == 0) lp[(bS + row) * NHEADS + h] = ls;
#pragma unroll
      for (int dg = 0; dg < 8; ++dg)
        op[(bS + row) * HDIM + h * HD + dg * 16 + l16] = (bf16)o[qt][dg][i];
    }
}

// ---------------- combine split-K partials: ctx = (o0+o1)/(l0+l1), in-place op0 ----
__global__ void k_combine(bf16* __restrict__ op0, const bf16* __restrict__ op1,
                          const float* __restrict__ lpart, int Mtot) {
  const int idx = (blockIdx.x * blockDim.x + threadIdx.x) * 4;
  const int row = idx >> 10;            // HDIM=1024
  const int h = (idx & 1023) >> 7;
  const float l = lpart[row * NHEADS + h] +
                  lpart[(size_t)Mtot * NHEADS + row * NHEADS + h];
  const float inv = 1.0f / l;
  bf16x4 a = *(const bf16x4*)&op0[idx];
  bf16x4 b = *(const bf16x4*)&op1[idx];
  bf16x4 o;
#pragma unroll
  for (int j = 0; j < 4; ++j) o[j] = (bf16)(((float)a[j] + (float)b[j]) * inv);
  *(bf16x4*)&op0[idx] = o;
}

// ---------------- fused meta: GEMM1+LN1+ReLU (h1 in LDS) -> GEMM2+LN2+ReLU+dot+out
__global__ __launch_bounds__(256) void k_meta12(
    const bf16* __restrict__ A1, const bf16* __restrict__ A2,
    const bf16* __restrict__ Bw1, const float* __restrict__ b1,
    const float* __restrict__ g1, const float* __restrict__ be1,
    const bf16* __restrict__ Bw2, const float* __restrict__ b2,
    const float* __restrict__ g2, const float* __restrict__ be2,
    const float* __restrict__ w3, const float* __restrict__ b3,
    const int* __restrict__ tok, const int* __restrict__ msk,
    const float* __restrict__ imp, float* __restrict__ out) {
  __shared__ char smem[44032];
  __shared__ float part_s[64][4];
  __shared__ float part_q[64][4];
  bf16 (*As)[40]  = (bf16(*)[40])smem;                 // phase1: 5120 B
  bf16 (*Bs)[40]  = (bf16(*)[40])(smem + 5120);        // phase1: 20480 B
  bf16 (*h1s)[264] = (bf16(*)[264])smem;               // phase2: 33792 B
  bf16 (*Bs2)[40] = (bf16(*)[40])(smem + 33792);       // phase2: 10240 B
  const int tid = threadIdx.x;
  const int w = tid >> 6, lane = tid & 63;
  const int quad = lane >> 4, l16 = lane & 15;
  const int tm = blockIdx.x * 64;
  const int lr = tid >> 2, lc = (tid & 3) * 8;

  // ---- phase 1: y1 = [x|att] @ w1^T, 64x256 tile ----
  f32x4 acc[4][4] = {};
  for (int k0 = 0; k0 < 2048; k0 += 32) {
    const int kg = k0 + lc;
    const bf16* ap = (kg < 1024) ? (A1 + (size_t)(tm + lr) * 1024 + kg)
                                 : (A2 + (size_t)(tm + lr) * 1024 + (kg - 1024));
    *(bf16x8*)&As[lr][lc] = *(const bf16x8*)ap;
#pragma unroll
    for (int it = 0; it < 4; ++it)
      *(bf16x8*)&Bs[lr + it * 64][lc] =
          *(const bf16x8*)(Bw1 + (size_t)(lr + it * 64) * 2048 + kg);
    __syncthreads();
    bf16x8 af[4], bfr[4];
#pragma unroll
    for (int mt = 0; mt < 4; ++mt) af[mt] = *(const bf16x8*)&As[mt * 16 + l16][quad * 8];
#pragma unroll
    for (int nt = 0; nt < 4; ++nt)
      bfr[nt] = *(const bf16x8*)&Bs[w * 64 + nt * 16 + l16][quad * 8];
#pragma unroll
    for (int mt = 0; mt < 4; ++mt)
#pragma unroll
      for (int nt = 0; nt < 4; ++nt)
        acc[mt][nt] = mfma16(af[mt], bfr[nt], acc[mt][nt]);
    __syncthreads();
  }

  float bv[4], gv[4], bev[4];
#pragma unroll
  for (int nt = 0; nt < 4; ++nt) {
    const int col = w * 64 + nt * 16 + l16;
    bv[nt] = b1[col]; gv[nt] = g1[col]; bev[nt] = be1[col];
  }
#pragma unroll
  for (int mt = 0; mt < 4; ++mt)
#pragma unroll
    for (int i = 0; i < 4; ++i) {
      float s = 0.f, q = 0.f;
#pragma unroll
      for (int nt = 0; nt < 4; ++nt) {
        const float v = acc[mt][nt][i] + bv[nt];
        s += v; q += v * v;
      }
#pragma unroll
      for (int off = 1; off < 16; off <<= 1) { s += __shfl_xor(s, off); q += __shfl_xor(q, off); }
      if (l16 == 0) {
        const int row = mt * 16 + quad * 4 + i;
        part_s[row][w] = s; part_q[row][w] = q;
      }
    }
  __syncthreads();   // parts ready; all Bs/As reads done -> safe to overwrite with h1s
#pragma unroll
  for (int mt = 0; mt < 4; ++mt)
#pragma unroll
    for (int i = 0; i < 4; ++i) {
      const int row = mt * 16 + quad * 4 + i;
      const float4 ps = *(const float4*)part_s[row];
      const float4 pq = *(const float4*)part_q[row];
      const float sum = ps.x + ps.y + ps.z + ps.w;
      const float sq = pq.x + pq.y + pq.z + pq.w;
      const float mean = sum / MD1;
      const float var = sq / MD1 - mean * mean;
      const float r = rsqrtf(var + LNEPS);
#pragma unroll
      for (int nt = 0; nt < 4; ++nt) {
        const int col = w * 64 + nt * 16 + l16;
        const float v = acc[mt][nt][i] + bv[nt];
        const float t = (v - mean) * r * gv[nt] + bev[nt];
        h1s[row][col] = (bf16)fmaxf(t, 0.f);
      }
    }
  __syncthreads();

  // ---- phase 2: y2 = h1 @ w2^T, 64x128; wave w owns rows [16w,16w+16), all cols ----
  f32x4 acc2[8] = {};
  for (int k0 = 0; k0 < MD1; k0 += 32) {
    const int kg = k0 + lc;
#pragma unroll
    for (int it = 0; it < 2; ++it)
      *(bf16x8*)&Bs2[lr + it * 64][lc] =
          *(const bf16x8*)(Bw2 + (size_t)(lr + it * 64) * MD1 + kg);
    __syncthreads();
    bf16x8 af = *(const bf16x8*)&h1s[w * 16 + l16][k0 + quad * 8];
#pragma unroll
    for (int nt = 0; nt < 8; ++nt) {
      bf16x8 bfr = *(const bf16x8*)&Bs2[nt * 16 + l16][quad * 8];
      acc2[nt] = mfma16(af, bfr, acc2[nt]);
    }
    __syncthreads();
  }

  float bv2[8], gv2[8], bev2[8], w3v[8];
#pragma unroll
  for (int nt = 0; nt < 8; ++nt) {
    const int col = nt * 16 + l16;
    bv2[nt] = b2[col]; gv2[nt] = g2[col]; bev2[nt] = be2[col]; w3v[nt] = w3[col];
  }
  const float b3v = b3[0];
#pragma unroll
  for (int i = 0; i < 4; ++i) {
    float s = 0.f, q = 0.f;
#pragma unroll
    for (int nt = 0; nt < 8; ++nt) {
      const float v = acc2[nt][i] + bv2[nt];
      s += v; q += v * v;
    }
#pragma unroll
    for (int off = 1; off < 16; off <<= 1) { s += __shfl_xor(s, off); q += __shfl_xor(q, off); }
    const float mean = s / MD2;
    const float var = q / MD2 - mean * mean;
    const float r = rsqrtf(var + LNEPS);
    float d = 0.f;
#pragma unroll
    for (int nt = 0; nt < 8; ++nt) {
      const float v = acc2[nt][i] + bv2[nt];
      const float t = (v - mean) * r * gv2[nt] + bev2[nt];
      d += fmaxf(t, 0.f) * w3v[nt];
    }
#pragma unroll
    for (int off = 1; off < 16; off <<= 1) d += __shfl_xor(d, off);
    if (l16 == 0) {
      const int row = tm + w * 16 + quad * 4 + i;
      const float base = d + b3v;
      float wt = base * (1.f + imp[tok[row]]);
      wt = fminf(fmaxf(wt, 0.1f), 5.0f);
      out[row] = msk[row] ? wt : 0.f;
    }
  }
}

// ---------------- launch ----------------
extern "C" void kernel_launch(void* const* d_in, const int* in_sizes, int n_in,
                              void* d_out, int out_size, void* d_ws, size_t ws_size,
                              hipStream_t stream) {
  const float* hs  = (const float*)d_in[0];
  const int*   tok = (const int*)d_in[1];
  const int*   msk = (const int*)d_in[2];
  const float* pos = (const float*)d_in[3];
  const float* inw = (const float*)d_in[4];
  const float* inb = (const float*)d_in[5];
  const float* ow  = (const float*)d_in[6];
  const float* ob  = (const float*)d_in[7];
  const float* w1  = (const float*)d_in[8];
  const float* b1  = (const float*)d_in[9];
  const float* g1  = (const float*)d_in[10];
  const float* be1 = (const float*)d_in[11];
  const float* w2  = (const float*)d_in[12];
  const float* b2  = (const float*)d_in[13];
  const float* g2  = (const float*)d_in[14];
  const float* be2 = (const float*)d_in[15];
  const float* w3  = (const float*)d_in[16];
  const float* b3  = (const float*)d_in[17];
  const float* imp = (const float*)d_in[18];

  const int SH = in_sizes[3];
  const int S  = SH / HDIM;
  const int Bsz = in_sizes[0] / SH;
  const int M = Bsz * S;

  char* ws = (char*)d_ws;
  const size_t MB2 = (size_t)M * HDIM * 2;
  size_t off = 0;
  bf16* xbf = (bf16*)(ws + off);  off += MB2;
  bf16* Qb  = (bf16*)(ws + off);  off += MB2;   // reused as attbf after flash
  bf16* Kb  = (bf16*)(ws + off);  off += MB2;
  bf16* VTb = (bf16*)(ws + off);  off += MB2;
  bf16* op0 = (bf16*)(ws + off);  off += MB2;   // split-0 partial -> combined ctx
  bf16* op1 = (bf16*)(ws + off);  off += MB2;   // split-1 partial
  bf16* winp = (bf16*)(ws + off); off += (size_t)3 * HDIM * HDIM * 2;
  bf16* wout = (bf16*)(ws + off); off += (size_t)HDIM * HDIM * 2;
  bf16* w1b = (bf16*)(ws + off);  off += (size_t)MD1 * 2 * HDIM * 2;
  bf16* w2b = (bf16*)(ws + off);  off += (size_t)MD2 * MD1 * 2;
  float* lpart = (float*)(ws + off); off += (size_t)2 * M * NHEADS * 4;
  bf16* attbf = Qb;

  const int nprep = M * HDIM;
  const int n0 = 3 * HDIM * HDIM, n1 = HDIM * HDIM, n2 = MD1 * 2 * HDIM, n3 = MD2 * MD1;
  k_prep_all<<<(nprep + n0 + n1 + n2 + n3) / 4 / 256, 256, 0, stream>>>(
      hs, pos, xbf, SH, nprep, inw, winp, n0, ow, wout, n1, w1, w1b, n2, w2, w2b, n3);
  k_gemm_qkv<<<dim3(M / 128, (3 * HDIM) / 128), 256, 0, stream>>>(
      xbf, winp, inb, Qb, Kb, VTb, S, HDIM);
  k_flash<<<dim3(S / 128, Bsz * NHEADS, 2), 256, 0, stream>>>(
      Qb, Kb, VTb, msk, op0, lpart, S, M);
  k_combine<<<(M * HDIM / 4) / 256, 256, 0, stream>>>(op0, op1, lpart, M);
  k_gemm128<true><<<dim3(M / 128, HDIM / 128), 256, 0, stream>>>(
      op0, wout, ob, attbf, HDIM, HDIM);
  k_meta12<<<M / 64, 256, 0, stream>>>(xbf, attbf, w1b, b1, g1, be1,
                                       w2b, b2, g2, be2, w3, b3, tok, msk, imp,
                                       (float*)d_out);
}

// Round 9
// 382.665 us; speedup vs baseline: 1.1383x; 1.1383x over previous
//
#include <hip/hip_runtime.h>
#include <hip/hip_bf16.h>
#include <math.h>

typedef __bf16 bf16;
typedef bf16 bf16x8 __attribute__((ext_vector_type(8)));
typedef bf16 bf16x4 __attribute__((ext_vector_type(4)));
typedef float f32x4 __attribute__((ext_vector_type(4)));

#define HDIM 1024
#define NHEADS 8
#define HD 128
#define MD1 256
#define MD2 128
#define LNEPS 1e-5f

__device__ __forceinline__ f32x4 mfma16(bf16x8 a, bf16x8 b, f32x4 c) {
  return __builtin_amdgcn_mfma_f32_16x16x32_bf16(a, b, c, 0, 0, 0);
}

__device__ __forceinline__ void gload_lds16(const bf16* g, bf16* l) {
  __builtin_amdgcn_global_load_lds(
      (const __attribute__((address_space(1))) void*)g,
      (__attribute__((address_space(3))) void*)l, 16, 0, 0);
}

// ---------------- fused prep: x=hs+pos cast, + all weight converts ----------------
__global__ void k_prep_all(
    const float* __restrict__ hs, const float* __restrict__ pos,
    bf16* __restrict__ xbf, int SH, int nprep,
    const float* __restrict__ s0, bf16* __restrict__ d0, int n0,
    const float* __restrict__ s1, bf16* __restrict__ d1, int n1,
    const float* __restrict__ s2, bf16* __restrict__ d2, int n2,
    const float* __restrict__ s3, bf16* __restrict__ d3, int n3) {
  int i = (blockIdx.x * blockDim.x + threadIdx.x) * 4;
  if (i < nprep) {
    float4 a = *(const float4*)(hs + i);
    float4 p = *(const float4*)(pos + (i % SH));
    bf16x4 o;
    o[0] = (bf16)(a.x + p.x); o[1] = (bf16)(a.y + p.y);
    o[2] = (bf16)(a.z + p.z); o[3] = (bf16)(a.w + p.w);
    *(bf16x4*)(xbf + i) = o;
    return;
  }
  int j = i - nprep;
  const float* s; bf16* d;
  if (j < n0)                { s = s0 + j; d = d0 + j; }
  else if (j < n0 + n1)      { s = s1 + (j - n0); d = d1 + (j - n0); }
  else if (j < n0 + n1 + n2) { s = s2 + (j - n0 - n1); d = d2 + (j - n0 - n1); }
  else                       { s = s3 + (j - n0 - n1 - n2); d = d3 + (j - n0 - n1 - n2); }
  float4 v = *(const float4*)s;
  bf16x4 o;
  o[0] = (bf16)v.x; o[1] = (bf16)v.y; o[2] = (bf16)v.z; o[3] = (bf16)v.w;
  *(bf16x4*)d = o;
}

// ---------------- b1' = b1 + w1b @ ob (fp32, tiny) ----------------
__global__ void k_b1p(const float* __restrict__ w1, const float* __restrict__ ob,
                      const float* __restrict__ b1, float* __restrict__ b1p) {
  const int t = threadIdx.x;
  const int n = blockIdx.x * 64 + (t >> 2);
  const int jq = t & 3;
  const float* row = w1 + (size_t)n * 2048 + 1024 + jq * 256;
  const float* obp = ob + jq * 256;
  float acc = 0.f;
  for (int j = 0; j < 256; j += 4) {
    float4 a = *(const float4*)(row + j);
    float4 o = *(const float4*)(obp + j);
    acc += a.x * o.x + a.y * o.y + a.z * o.z + a.w * o.w;
  }
  acc += __shfl_xor(acc, 1);
  acc += __shfl_xor(acc, 2);
  if (jq == 0) b1p[n] = b1[n] + acc;
}

// ---------------- W' = w1b @ ow : [256 x 1024] bf16 ----------------
__global__ __launch_bounds__(256) void k_wprime(
    const bf16* __restrict__ w1full, const bf16* __restrict__ ow,
    bf16* __restrict__ Wp) {
  __shared__ bf16 Bst[64][40];
  const int tid = threadIdx.x;
  const int w = tid >> 6, lane = tid & 63;
  const int quad = lane >> 4, l16 = lane & 15;
  const int d0 = blockIdx.x * 64, n0 = blockIdx.y * 64;
  const bf16* arow = w1full + (size_t)(n0 + w * 16 + l16) * 2048 + 1024;
  f32x4 acc[4] = {};
  for (int k0 = 0; k0 < 1024; k0 += 32) {
    const int kk = tid >> 3, dd8 = (tid & 7) * 8;
    bf16x8 v = *(const bf16x8*)(ow + (size_t)(k0 + kk) * 1024 + d0 + dd8);
    __syncthreads();
#pragma unroll
    for (int jj = 0; jj < 8; ++jj) Bst[dd8 + jj][kk] = v[jj];
    __syncthreads();
    bf16x8 af = *(const bf16x8*)(arow + k0 + quad * 8);
#pragma unroll
    for (int dg = 0; dg < 4; ++dg) {
      bf16x8 bfr = *(const bf16x8*)&Bst[dg * 16 + l16][quad * 8];
      acc[dg] = mfma16(af, bfr, acc[dg]);
    }
  }
#pragma unroll
  for (int dg = 0; dg < 4; ++dg) {
    const int d = d0 + dg * 16 + l16;
#pragma unroll
    for (int i = 0; i < 4; ++i)
      Wp[(size_t)(n0 + w * 16 + quad * 4 + i) * 1024 + d] = (bf16)acc[dg][i];
  }
}

// ---------------- QKV GEMM, 128x128 tile, BK=64: Q/K row-major, V transposed ------
__global__ __launch_bounds__(256) void k_gemm_qkv(
    const bf16* __restrict__ A, const bf16* __restrict__ Bw,
    const float* __restrict__ bias, bf16* __restrict__ Qo,
    bf16* __restrict__ Ko, bf16* __restrict__ VTo, int S, int K) {
  __shared__ bf16 As[128 * 64];
  __shared__ bf16 Bs[128 * 64];
  const int tid = threadIdx.x;
  const int w = tid >> 6, lane = tid & 63;
  const int quad = lane >> 4, l16 = lane & 15;
  const int wm = w & 1, wn = w >> 1;
  const int tm = blockIdx.x * 128, tn = blockIdx.y * 128;

  // staging map: call c stages rows c*32..c*32+31; thread covers k-block (t&7)^f(row)
  const int tq = tid >> 3, t8 = tid & 7;
  const bf16 *ap[4], *bp[4];
#pragma unroll
  for (int c = 0; c < 4; ++c) {
    const int r = c * 32 + tq;
    const int col = ((t8 ^ ((r ^ (r >> 3)) & 7)) * 8);
    ap[c] = A + (size_t)(tm + r) * K + col;
    bp[c] = Bw + (size_t)(tn + r) * K + col;
  }
  bf16* lA = As + (size_t)tid * 8;
  bf16* lB = Bs + (size_t)tid * 8;

  int fam[4], fbn[4], ram[4], rbn[4];
#pragma unroll
  for (int mt = 0; mt < 4; ++mt) {
    const int r = wm * 64 + mt * 16 + l16;
    ram[mt] = r; fam[mt] = (r ^ (r >> 3)) & 7;
    const int r2 = wn * 64 + mt * 16 + l16;
    rbn[mt] = r2; fbn[mt] = (r2 ^ (r2 >> 3)) & 7;
  }

  f32x4 acc[4][4] = {};
  for (int k0 = 0; k0 < K; k0 += 64) {
#pragma unroll
    for (int c = 0; c < 4; ++c) {
      gload_lds16(ap[c] + k0, lA + c * 2048);
      gload_lds16(bp[c] + k0, lB + c * 2048);
    }
    __syncthreads();
#pragma unroll
    for (int ks = 0; ks < 2; ++ks) {
      bf16x8 af[4], bfr[4];
#pragma unroll
      for (int mt = 0; mt < 4; ++mt)
        af[mt] = *(const bf16x8*)&As[ram[mt] * 64 + (((ks * 4 + quad) ^ fam[mt]) << 3)];
#pragma unroll
      for (int nt = 0; nt < 4; ++nt)
        bfr[nt] = *(const bf16x8*)&Bs[rbn[nt] * 64 + (((ks * 4 + quad) ^ fbn[nt]) << 3)];
#pragma unroll
      for (int mt = 0; mt < 4; ++mt)
#pragma unroll
        for (int nt = 0; nt < 4; ++nt)
          acc[mt][nt] = mfma16(af[mt], bfr[nt], acc[mt][nt]);
    }
    __syncthreads();
  }

  const int region = tn >> 10;            // 0:Q 1:K 2:V
  const int btile = tm / S, s0 = tm % S;
#pragma unroll
  for (int nt = 0; nt < 4; ++nt) {
    const int col = tn + wn * 64 + nt * 16 + l16;
    const float bv = bias[col];
#pragma unroll
    for (int mt = 0; mt < 4; ++mt) {
      if (region == 2) {
        const int d = col - 2048, hh = d >> 7, dd = d & 127;
        const int sb = s0 + wm * 64 + mt * 16 + quad * 4;
        bf16x4 o4;
#pragma unroll
        for (int i = 0; i < 4; ++i) o4[i] = (bf16)(acc[mt][nt][i] + bv);
        *(bf16x4*)&VTo[((size_t)(btile * NHEADS + hh) * HD + dd) * S + sb] = o4;
      } else {
        bf16* dst = (region == 0) ? Qo : Ko;
        const int cc = (region == 0) ? col : col - 1024;
#pragma unroll
        for (int i = 0; i < 4; ++i) {
          const int row = tm + wm * 64 + mt * 16 + quad * 4 + i;
          dst[(size_t)row * HDIM + cc] = (bf16)(acc[mt][nt][i] + bv);
        }
      }
    }
  }
}

// ---------------- flash attention: transposed-QK (S^T = K Q^T) ----------------
// C-layout of S^T gives lane=q, rows=keys -> exp results pack into b64 Ps writes.
// Ps: per (wave,qt) 16q x 64key, 16B-granule XOR swizzle: granule(key>>3) ^ (q&7).
__global__ __launch_bounds__(256) void k_flash(
    const bf16* __restrict__ Qg, const bf16* __restrict__ Kg,
    const bf16* __restrict__ VTg, const int* __restrict__ mask,
    bf16* __restrict__ ctx, int S) {
  __shared__ bf16 Ks[64][136];
  __shared__ bf16 Vt[128 * 64];
  __shared__ bf16 Ps[8 * 1024];
  __shared__ float biass[64];
  const int tid = threadIdx.x, w = tid >> 6, lane = tid & 63;
  const int quad = lane >> 4, l16 = lane & 15;
  const int bh = blockIdx.y, b = bh / NHEADS, h = bh % NHEADS;
  const int q0 = blockIdx.x * 128 + w * 32;
  const size_t bS = (size_t)b * S;
  const bf16* Qb = Qg + bS * HDIM + h * HD;
  const bf16* Kb = Kg + bS * HDIM + h * HD;
  const bf16* Vb = VTg + (size_t)bh * HD * S;
  const int* mrow = mask + bS;

  bf16x8 qf[2][4];
#pragma unroll
  for (int qt = 0; qt < 2; ++qt)
#pragma unroll
    for (int s = 0; s < 4; ++s)
      qf[qt][s] = *(const bf16x8*)(Qb + (size_t)(q0 + qt * 16 + l16) * HDIM + s * 32 + quad * 8);

  float lsum[2] = {0.f, 0.f};
  f32x4 o[2][8] = {};
  const float scale2 = 0.08838834764831845f * 1.4426950408889634f;

  const int nchunk = S / 64;
  bf16x8 kreg[4], vreg[4];
  int mreg = (tid < 64) ? mrow[tid] : 0;
#pragma unroll
  for (int it = 0; it < 4; ++it) {
    const int cid = tid + it * 256;
    kreg[it] = *(const bf16x8*)(Kb + (size_t)(cid >> 4) * HDIM + (cid & 15) * 8);
    vreg[it] = *(const bf16x8*)(Vb + (size_t)(cid >> 3) * S + (cid & 7) * 8);
  }

  for (int c0 = 0; c0 < nchunk; ++c0) {
    __syncthreads();
#pragma unroll
    for (int it = 0; it < 4; ++it) {
      const int cid = tid + it * 256;
      *(bf16x8*)&Ks[cid >> 4][(cid & 15) * 8] = kreg[it];
      const int vd = cid >> 3, vkb = cid & 7;
      *(bf16x8*)&Vt[vd * 64 + ((vkb ^ (vd & 7)) << 3)] = vreg[it];
    }
    if (tid < 64) biass[tid] = mreg ? 0.f : -1e9f;
    __syncthreads();
    const int key0n = ((c0 + 1 < nchunk) ? c0 + 1 : c0) * 64;
    if (tid < 64) mreg = mrow[key0n + tid];
#pragma unroll
    for (int it = 0; it < 4; ++it) {
      const int cid = tid + it * 256;
      kreg[it] = *(const bf16x8*)(Kb + (size_t)(key0n + (cid >> 4)) * HDIM + (cid & 15) * 8);
      vreg[it] = *(const bf16x8*)(Vb + (size_t)(cid >> 3) * S + key0n + (cid & 7) * 8);
    }
    // ---- S^T = K Q^T : A = K-frag (lane=key), B = Q-frag (lane=q) ----
    f32x4 s4[2][4] = {};
#pragma unroll
    for (int g = 0; g < 4; ++g)
#pragma unroll
      for (int s = 0; s < 4; ++s) {
        bf16x8 kf = *(const bf16x8*)&Ks[g * 16 + l16][s * 32 + quad * 8];
        s4[0][g] = mfma16(kf, qf[0][s], s4[0][g]);
        s4[1][g] = mfma16(kf, qf[1][s], s4[1][g]);
      }
    // ---- softmax + packed transpose-write: lane holds q=l16, keys g*16+quad*4+i ----
#pragma unroll
    for (int qt = 0; qt < 2; ++qt) {
      const int base = (w * 2 + qt) * 1024;
#pragma unroll
      for (int g = 0; g < 4; ++g) {
        bf16x4 pk;
#pragma unroll
        for (int i = 0; i < 4; ++i) {
          const float p = exp2f(fmaf(s4[qt][g][i], scale2, biass[g * 16 + quad * 4 + i]));
          lsum[qt] += p;
          pk[i] = (bf16)p;
        }
        const int sw = (2 * g + (quad >> 1)) ^ (l16 & 7);
        *(bf16x4*)&Ps[base + l16 * 64 + sw * 8 + (quad & 1) * 4] = pk;
      }
    }
    // ---- PV: A = P (lane=q), B = V^T frag (lane=d) ----
#pragma unroll
    for (int kk = 0; kk < 2; ++kk) {
      const int kb = kk * 4 + quad;
      bf16x8 pf0 = *(const bf16x8*)&Ps[(w * 2) * 1024 + l16 * 64 + ((kb ^ (l16 & 7)) << 3)];
      bf16x8 pf1 = *(const bf16x8*)&Ps[(w * 2 + 1) * 1024 + l16 * 64 + ((kb ^ (l16 & 7)) << 3)];
#pragma unroll
      for (int dg = 0; dg < 8; ++dg) {
        const int d = dg * 16 + l16;
        bf16x8 vf = *(const bf16x8*)&Vt[d * 64 + ((kb ^ (d & 7)) << 3)];
        o[0][dg] = mfma16(pf0, vf, o[0][dg]);
        o[1][dg] = mfma16(pf1, vf, o[1][dg]);
      }
    }
  }

  // lsum: lane holds partial for q=l16 (this quad's keys) -> reduce over quads
#pragma unroll
  for (int qt = 0; qt < 2; ++qt) {
    lsum[qt] += __shfl_xor(lsum[qt], 16);
    lsum[qt] += __shfl_xor(lsum[qt], 32);
  }
#pragma unroll
  for (int qt = 0; qt < 2; ++qt)
#pragma unroll
    for (int i = 0; i < 4; ++i) {
      const float ls = __shfl(lsum[qt], quad * 4 + i);
      const float inv = 1.0f / ls;
      const int row = q0 + qt * 16 + quad * 4 + i;
#pragma unroll
      for (int dg = 0; dg < 8; ++dg)
        ctx[(bS + row) * HDIM + h * HD + dg * 16 + l16] = (bf16)(o[qt][dg][i] * inv);
    }
}

// ---------------- fused meta: [x|ctx]@[w1a|W']^T +b1' -> LN -> ReLU -> GEMM2 -> out
__global__ __launch_bounds__(256) void k_meta12(
    const bf16* __restrict__ A1, const bf16* __restrict__ A2,
    const bf16* __restrict__ Bw1, const bf16* __restrict__ Wp,
    const float* __restrict__ b1p, const float* __restrict__ g1,
    const float* __restrict__ be1,
    const bf16* __restrict__ Bw2, const float* __restrict__ b2,
    const float* __restrict__ g2, const float* __restrict__ be2,
    const float* __restrict__ w3, const float* __restrict__ b3,
    const int* __restrict__ tok, const int* __restrict__ msk,
    const float* __restrict__ imp, float* __restrict__ out) {
  __shared__ char smem[44032];
  __shared__ float part_s[64][4];
  __shared__ float part_q[64][4];
  bf16 (*As)[40]  = (bf16(*)[40])smem;
  bf16 (*Bs)[40]  = (bf16(*)[40])(smem + 5120);
  bf16 (*h1s)[264] = (bf16(*)[264])smem;
  bf16 (*Bs2)[40] = (bf16(*)[40])(smem + 33792);
  const int tid = threadIdx.x;
  const int w = tid >> 6, lane = tid & 63;
  const int quad = lane >> 4, l16 = lane & 15;
  const int tm = blockIdx.x * 64;
  const int lr = tid >> 2, lc = (tid & 3) * 8;

  f32x4 acc[4][4] = {};
  for (int k0 = 0; k0 < 2048; k0 += 32) {
    const int kg = k0 + lc;
    const bf16* ap = (kg < 1024) ? (A1 + (size_t)(tm + lr) * 1024 + kg)
                                 : (A2 + (size_t)(tm + lr) * 1024 + (kg - 1024));
    *(bf16x8*)&As[lr][lc] = *(const bf16x8*)ap;
#pragma unroll
    for (int it = 0; it < 4; ++it) {
      const int row = lr + it * 64;
      const bf16* bp = (kg < 1024) ? (Bw1 + (size_t)row * 2048 + kg)
                                   : (Wp + (size_t)row * 1024 + (kg - 1024));
      *(bf16x8*)&Bs[row][lc] = *(const bf16x8*)bp;
    }
    __syncthreads();
    bf16x8 af[4], bfr[4];
#pragma unroll
    for (int mt = 0; mt < 4; ++mt) af[mt] = *(const bf16x8*)&As[mt * 16 + l16][quad * 8];
#pragma unroll
    for (int nt = 0; nt < 4; ++nt)
      bfr[nt] = *(const bf16x8*)&Bs[w * 64 + nt * 16 + l16][quad * 8];
#pragma unroll
    for (int mt = 0; mt < 4; ++mt)
#pragma unroll
      for (int nt = 0; nt < 4; ++nt)
        acc[mt][nt] = mfma16(af[mt], bfr[nt], acc[mt][nt]);
    __syncthreads();
  }

  float bv[4], gv[4], bev[4];
#pragma unroll
  for (int nt = 0; nt < 4; ++nt) {
    const int col = w * 64 + nt * 16 + l16;
    bv[nt] = b1p[col]; gv[nt] = g1[col]; bev[nt] = be1[col];
  }
#pragma unroll
  for (int mt = 0; mt < 4; ++mt)
#pragma unroll
    for (int i = 0; i < 4; ++i) {
      float s = 0.f, q = 0.f;
#pragma unroll
      for (int nt = 0; nt < 4; ++nt) {
        const float v = acc[mt][nt][i] + bv[nt];
        s += v; q += v * v;
      }
#pragma unroll
      for (int off = 1; off < 16; off <<= 1) { s += __shfl_xor(s, off); q += __shfl_xor(q, off); }
      if (l16 == 0) {
        const int row = mt * 16 + quad * 4 + i;
        part_s[row][w] = s; part_q[row][w] = q;
      }
    }
  __syncthreads();
#pragma unroll
  for (int mt = 0; mt < 4; ++mt)
#pragma unroll
    for (int i = 0; i < 4; ++i) {
      const int row = mt * 16 + quad * 4 + i;
      const float4 ps = *(const float4*)part_s[row];
      const float4 pq = *(const float4*)part_q[row];
      const float sum = ps.x + ps.y + ps.z + ps.w;
      const float sq = pq.x + pq.y + pq.z + pq.w;
      const float mean = sum / MD1;
      const float var = sq / MD1 - mean * mean;
      const float r = rsqrtf(var + LNEPS);
#pragma unroll
      for (int nt = 0; nt < 4; ++nt) {
        const int col = w * 64 + nt * 16 + l16;
        const float v = acc[mt][nt][i] + bv[nt];
        const float t = (v - mean) * r * gv[nt] + bev[nt];
        h1s[row][col] = (bf16)fmaxf(t, 0.f);
      }
    }
  __syncthreads();

  f32x4 acc2[8] = {};
  for (int k0 = 0; k0 < MD1; k0 += 32) {
    const int kg = k0 + lc;
#pragma unroll
    for (int it = 0; it < 2; ++it)
      *(bf16x8*)&Bs2[lr + it * 64][lc] =
          *(const bf16x8*)(Bw2 + (size_t)(lr + it * 64) * MD1 + kg);
    __syncthreads();
    bf16x8 af = *(const bf16x8*)&h1s[w * 16 + l16][k0 + quad * 8];
#pragma unroll
    for (int nt = 0; nt < 8; ++nt) {
      bf16x8 bfr = *(const bf16x8*)&Bs2[nt * 16 + l16][quad * 8];
      acc2[nt] = mfma16(af, bfr, acc2[nt]);
    }
    __syncthreads();
  }

  float bv2[8], gv2[8], bev2[8], w3v[8];
#pragma unroll
  for (int nt = 0; nt < 8; ++nt) {
    const int col = nt * 16 + l16;
    bv2[nt] = b2[col]; gv2[nt] = g2[col]; bev2[nt] = be2[col]; w3v[nt] = w3[col];
  }
  const float b3v = b3[0];
#pragma unroll
  for (int i = 0; i < 4; ++i) {
    float s = 0.f, q = 0.f;
#pragma unroll
    for (int nt = 0; nt < 8; ++nt) {
      const float v = acc2[nt][i] + bv2[nt];
      s += v; q += v * v;
    }
#pragma unroll
    for (int off = 1; off < 16; off <<= 1) { s += __shfl_xor(s, off); q += __shfl_xor(q, off); }
    const float mean = s / MD2;
    const float var = q / MD2 - mean * mean;
    const float r = rsqrtf(var + LNEPS);
    float d = 0.f;
#pragma unroll
    for (int nt = 0; nt < 8; ++nt) {
      const float v = acc2[nt][i] + bv2[nt];
      const float t = (v - mean) * r * gv2[nt] + bev2[nt];
      d += fmaxf(t, 0.f) * w3v[nt];
    }
#pragma unroll
    for (int off = 1; off < 16; off <<= 1) d += __shfl_xor(d, off);
    if (l16 == 0) {
      const int row = tm + w * 16 + quad * 4 + i;
      float wt = (d + b3v) * (1.f + imp[tok[row]]);
      wt = fminf(fmaxf(wt, 0.1f), 5.0f);
      out[row] = msk[row] ? wt : 0.f;
    }
  }
}

// ---------------- launch ----------------
extern "C" void kernel_launch(void* const* d_in, const int* in_sizes, int n_in,
                              void* d_out, int out_size, void* d_ws, size_t ws_size,
                              hipStream_t stream) {
  const float* hs  = (const float*)d_in[0];
  const int*   tok = (const int*)d_in[1];
  const int*   msk = (const int*)d_in[2];
  const float* pos = (const float*)d_in[3];
  const float* inw = (const float*)d_in[4];
  const float* inb = (const float*)d_in[5];
  const float* ow  = (const float*)d_in[6];
  const float* ob  = (const float*)d_in[7];
  const float* w1  = (const float*)d_in[8];
  const float* b1  = (const float*)d_in[9];
  const float* g1  = (const float*)d_in[10];
  const float* be1 = (const float*)d_in[11];
  const float* w2  = (const float*)d_in[12];
  const float* b2  = (const float*)d_in[13];
  const float* g2  = (const float*)d_in[14];
  const float* be2 = (const float*)d_in[15];
  const float* w3  = (const float*)d_in[16];
  const float* b3  = (const float*)d_in[17];
  const float* imp = (const float*)d_in[18];

  const int SH = in_sizes[3];
  const int S  = SH / HDIM;
  const int Bsz = in_sizes[0] / SH;
  const int M = Bsz * S;

  char* ws = (char*)d_ws;
  const size_t MB2 = (size_t)M * HDIM * 2;
  size_t off = 0;
  bf16* xbf = (bf16*)(ws + off);  off += MB2;
  bf16* Qb  = (bf16*)(ws + off);  off += MB2;
  bf16* Kb  = (bf16*)(ws + off);  off += MB2;
  bf16* VTb = (bf16*)(ws + off);  off += MB2;
  bf16* ctx = (bf16*)(ws + off);  off += MB2;
  bf16* winp = (bf16*)(ws + off); off += (size_t)3 * HDIM * HDIM * 2;
  bf16* wout = (bf16*)(ws + off); off += (size_t)HDIM * HDIM * 2;
  bf16* w1b = (bf16*)(ws + off);  off += (size_t)MD1 * 2 * HDIM * 2;
  bf16* w2b = (bf16*)(ws + off);  off += (size_t)MD2 * MD1 * 2;
  bf16* Wp  = (bf16*)(ws + off);  off += (size_t)MD1 * HDIM * 2;
  float* b1p = (float*)(ws + off); off += (size_t)MD1 * 4;

  const int nprep = M * HDIM;
  const int n0 = 3 * HDIM * HDIM, n1 = HDIM * HDIM, n2 = MD1 * 2 * HDIM, n3 = MD2 * MD1;
  k_prep_all<<<(nprep + n0 + n1 + n2 + n3) / 4 / 256, 256, 0, stream>>>(
      hs, pos, xbf, SH, nprep, inw, winp, n0, ow, wout, n1, w1, w1b, n2, w2, w2b, n3);
  k_b1p<<<MD1 / 64, 256, 0, stream>>>(w1, ob, b1, b1p);
  k_wprime<<<dim3(HDIM / 64, MD1 / 64), 256, 0, stream>>>(w1b, wout, Wp);
  k_gemm_qkv<<<dim3(M / 128, (3 * HDIM) / 128), 256, 0, stream>>>(
      xbf, winp, inb, Qb, Kb, VTb, S, HDIM);
  k_flash<<<dim3(S / 128, Bsz * NHEADS), 256, 0, stream>>>(Qb, Kb, VTb, msk, ctx, S);
  k_meta12<<<M / 64, 256, 0, stream>>>(xbf, ctx, w1b, Wp, b1p, g1, be1,
                                       w2b, b2, g2, be2, w3, b3, tok, msk, imp,
                                       (float*)d_out);
}

// Round 10
// 372.302 us; speedup vs baseline: 1.1700x; 1.0278x over previous
//
#include <hip/hip_runtime.h>
#include <hip/hip_bf16.h>
#include <math.h>

typedef __bf16 bf16;
typedef bf16 bf16x8 __attribute__((ext_vector_type(8)));
typedef bf16 bf16x4 __attribute__((ext_vector_type(4)));
typedef float f32x4 __attribute__((ext_vector_type(4)));

#define HDIM 1024
#define NHEADS 8
#define HD 128
#define MD1 256
#define MD2 128
#define LNEPS 1e-5f

__device__ __forceinline__ f32x4 mfma16(bf16x8 a, bf16x8 b, f32x4 c) {
  return __builtin_amdgcn_mfma_f32_16x16x32_bf16(a, b, c, 0, 0, 0);
}

__device__ __forceinline__ void gload_lds16(const bf16* g, bf16* l) {
  __builtin_amdgcn_global_load_lds(
      (const __attribute__((address_space(1))) void*)g,
      (__attribute__((address_space(3))) void*)l, 16, 0, 0);
}

// ---------------- mega-prep: elementwise converts + W'=w1b@ow + b1'=b1+w1b@ob ----
// blocks [0, blocks_el): x=hs+pos cast + weight converts (inw, w1, w2)
// blocks [blocks_el, +64): W' MFMA (reads fp32 w1/ow, converts inline)
// blocks [+64, +68): b1'
__global__ __launch_bounds__(256) void k_prep_all(
    const float* __restrict__ hs, const float* __restrict__ pos,
    bf16* __restrict__ xbf, int SH, int nprep,
    const float* __restrict__ inwf, bf16* __restrict__ winp, int n0,
    const float* __restrict__ w1f, bf16* __restrict__ w1b, int n2,
    const float* __restrict__ w2f, bf16* __restrict__ w2b, int n3,
    const float* __restrict__ owf, const float* __restrict__ obf,
    const float* __restrict__ b1f, bf16* __restrict__ Wp,
    float* __restrict__ b1p, int blocks_el) {
  const int bid = blockIdx.x;
  const int tid = threadIdx.x;
  if (bid < blocks_el) {
    int i = (bid * 256 + tid) * 4;
    if (i < nprep) {
      float4 a = *(const float4*)(hs + i);
      float4 p = *(const float4*)(pos + (i % SH));
      bf16x4 o;
      o[0] = (bf16)(a.x + p.x); o[1] = (bf16)(a.y + p.y);
      o[2] = (bf16)(a.z + p.z); o[3] = (bf16)(a.w + p.w);
      *(bf16x4*)(xbf + i) = o;
      return;
    }
    int j = i - nprep;
    const float* s; bf16* d;
    if (j < n0)           { s = inwf + j; d = winp + j; }
    else if (j < n0 + n2) { s = w1f + (j - n0); d = w1b + (j - n0); }
    else                  { s = w2f + (j - n0 - n2); d = w2b + (j - n0 - n2); }
    float4 v = *(const float4*)s;
    bf16x4 o;
    o[0] = (bf16)v.x; o[1] = (bf16)v.y; o[2] = (bf16)v.z; o[3] = (bf16)v.w;
    *(bf16x4*)d = o;
    return;
  }
  if (bid < blocks_el + 64) {
    // ---- W' = bf16(w1b) @ bf16(ow) : [256 x 1024] ----
    __shared__ bf16 Bst[64][42];
    const int bid2 = bid - blocks_el;
    const int d0 = (bid2 & 15) * 64, n0w = (bid2 >> 4) * 64;
    const int w = tid >> 6, lane = tid & 63;
    const int quad = lane >> 4, l16 = lane & 15;
    const float* arow = w1f + (size_t)(n0w + w * 16 + l16) * 2048 + 1024;
    f32x4 acc[4] = {};
    for (int k0 = 0; k0 < 1024; k0 += 32) {
      const int kk = tid >> 3, dd8 = (tid & 7) * 8;
      float4 va = *(const float4*)(owf + (size_t)(k0 + kk) * 1024 + d0 + dd8);
      float4 vb = *(const float4*)(owf + (size_t)(k0 + kk) * 1024 + d0 + dd8 + 4);
      __syncthreads();
      Bst[dd8 + 0][kk] = (bf16)va.x; Bst[dd8 + 1][kk] = (bf16)va.y;
      Bst[dd8 + 2][kk] = (bf16)va.z; Bst[dd8 + 3][kk] = (bf16)va.w;
      Bst[dd8 + 4][kk] = (bf16)vb.x; Bst[dd8 + 5][kk] = (bf16)vb.y;
      Bst[dd8 + 6][kk] = (bf16)vb.z; Bst[dd8 + 7][kk] = (bf16)vb.w;
      __syncthreads();
      float4 fa = *(const float4*)(arow + k0 + quad * 8);
      float4 fb = *(const float4*)(arow + k0 + quad * 8 + 4);
      bf16x8 af;
      af[0] = (bf16)fa.x; af[1] = (bf16)fa.y; af[2] = (bf16)fa.z; af[3] = (bf16)fa.w;
      af[4] = (bf16)fb.x; af[5] = (bf16)fb.y; af[6] = (bf16)fb.z; af[7] = (bf16)fb.w;
#pragma unroll
      for (int dg = 0; dg < 4; ++dg) {
        bf16x8 bfr = *(const bf16x8*)&Bst[dg * 16 + l16][quad * 8];
        acc[dg] = mfma16(af, bfr, acc[dg]);
      }
    }
#pragma unroll
    for (int dg = 0; dg < 4; ++dg) {
      const int d = d0 + dg * 16 + l16;
#pragma unroll
      for (int i = 0; i < 4; ++i)
        Wp[(size_t)(n0w + w * 16 + quad * 4 + i) * 1024 + d] = (bf16)acc[dg][i];
    }
    return;
  }
  // ---- b1' = b1 + w1b @ ob ----
  const int bid3 = bid - blocks_el - 64;
  const int n = bid3 * 64 + (tid >> 2);
  const int jq = tid & 3;
  const float* row = w1f + (size_t)n * 2048 + 1024 + jq * 256;
  const float* obp = obf + jq * 256;
  float acc = 0.f;
  for (int j = 0; j < 256; j += 4) {
    float4 a = *(const float4*)(row + j);
    float4 o = *(const float4*)(obp + j);
    acc += a.x * o.x + a.y * o.y + a.z * o.z + a.w * o.w;
  }
  acc += __shfl_xor(acc, 1);
  acc += __shfl_xor(acc, 2);
  if (jq == 0) b1p[n] = b1f[n] + acc;
}

// ---------------- QKV GEMM, 128x128 tile, BK=64: Q/K row-major, V transposed ------
__global__ __launch_bounds__(256) void k_gemm_qkv(
    const bf16* __restrict__ A, const bf16* __restrict__ Bw,
    const float* __restrict__ bias, bf16* __restrict__ Qo,
    bf16* __restrict__ Ko, bf16* __restrict__ VTo, int S, int K) {
  __shared__ bf16 As[128 * 64];
  __shared__ bf16 Bs[128 * 64];
  const int tid = threadIdx.x;
  const int w = tid >> 6, lane = tid & 63;
  const int quad = lane >> 4, l16 = lane & 15;
  const int wm = w & 1, wn = w >> 1;
  const int tm = blockIdx.x * 128, tn = blockIdx.y * 128;

  const int tq = tid >> 3, t8 = tid & 7;
  const bf16 *ap[4], *bp[4];
#pragma unroll
  for (int c = 0; c < 4; ++c) {
    const int r = c * 32 + tq;
    const int col = ((t8 ^ ((r ^ (r >> 3)) & 7)) * 8);
    ap[c] = A + (size_t)(tm + r) * K + col;
    bp[c] = Bw + (size_t)(tn + r) * K + col;
  }
  bf16* lA = As + (size_t)tid * 8;
  bf16* lB = Bs + (size_t)tid * 8;

  int fam[4], fbn[4], ram[4], rbn[4];
#pragma unroll
  for (int mt = 0; mt < 4; ++mt) {
    const int r = wm * 64 + mt * 16 + l16;
    ram[mt] = r; fam[mt] = (r ^ (r >> 3)) & 7;
    const int r2 = wn * 64 + mt * 16 + l16;
    rbn[mt] = r2; fbn[mt] = (r2 ^ (r2 >> 3)) & 7;
  }

  f32x4 acc[4][4] = {};
  for (int k0 = 0; k0 < K; k0 += 64) {
#pragma unroll
    for (int c = 0; c < 4; ++c) {
      gload_lds16(ap[c] + k0, lA + c * 2048);
      gload_lds16(bp[c] + k0, lB + c * 2048);
    }
    __syncthreads();
#pragma unroll
    for (int ks = 0; ks < 2; ++ks) {
      bf16x8 af[4], bfr[4];
#pragma unroll
      for (int mt = 0; mt < 4; ++mt)
        af[mt] = *(const bf16x8*)&As[ram[mt] * 64 + (((ks * 4 + quad) ^ fam[mt]) << 3)];
#pragma unroll
      for (int nt = 0; nt < 4; ++nt)
        bfr[nt] = *(const bf16x8*)&Bs[rbn[nt] * 64 + (((ks * 4 + quad) ^ fbn[nt]) << 3)];
#pragma unroll
      for (int mt = 0; mt < 4; ++mt)
#pragma unroll
        for (int nt = 0; nt < 4; ++nt)
          acc[mt][nt] = mfma16(af[mt], bfr[nt], acc[mt][nt]);
    }
    __syncthreads();
  }

  const int region = tn >> 10;            // 0:Q 1:K 2:V
  const int btile = tm / S, s0 = tm % S;
#pragma unroll
  for (int nt = 0; nt < 4; ++nt) {
    const int col = tn + wn * 64 + nt * 16 + l16;
    const float bv = bias[col];
#pragma unroll
    for (int mt = 0; mt < 4; ++mt) {
      if (region == 2) {
        const int d = col - 2048, hh = d >> 7, dd = d & 127;
        const int sb = s0 + wm * 64 + mt * 16 + quad * 4;
        bf16x4 o4;
#pragma unroll
        for (int i = 0; i < 4; ++i) o4[i] = (bf16)(acc[mt][nt][i] + bv);
        *(bf16x4*)&VTo[((size_t)(btile * NHEADS + hh) * HD + dd) * S + sb] = o4;
      } else {
        bf16* dst = (region == 0) ? Qo : Ko;
        const int cc = (region == 0) ? col : col - 1024;
#pragma unroll
        for (int i = 0; i < 4; ++i) {
          const int row = tm + wm * 64 + mt * 16 + quad * 4 + i;
          dst[(size_t)row * HDIM + cc] = (bf16)(acc[mt][nt][i] + bv);
        }
      }
    }
  }
}

// ---------------- flash v5: transposed-QK + global_load_lds staging + XCD swizzle --
// Ks layout: row=key (128 el), granule gr holds d-block (gr&8)|((gr^f(key))&7),
// f(key)=(key^(key>>3))&7 -> gll dest lane-linear, reads 2-way max.
// Vt layout: el = d*64 + ((kb^(d&7))<<3)+klo, swizzle inverted in gll source.
__global__ __launch_bounds__(256) void k_flash(
    const bf16* __restrict__ Qg, const bf16* __restrict__ Kg,
    const bf16* __restrict__ VTg, const int* __restrict__ mask,
    bf16* __restrict__ ctx, int S) {
  __shared__ bf16 Ks[64 * 128];
  __shared__ bf16 Vt[128 * 64];
  __shared__ bf16 Ps[8 * 1024];
  __shared__ float biass[64];
  const int tid = threadIdx.x, w = tid >> 6, lane = tid & 63;
  const int quad = lane >> 4, l16 = lane & 15;
  // XCD-locality swizzle: all 16 q-blocks of one (b,h) on one XCD (bid%8 heuristic)
  const int p = blockIdx.x;
  const int bh = (p & 7) * 4 + ((p >> 3) >> 4);
  const int qb = (p >> 3) & 15;
  const int b = bh / NHEADS, h = bh % NHEADS;
  const int q0 = qb * 128 + w * 32;
  const size_t bS = (size_t)b * S;
  const bf16* Qb = Qg + bS * HDIM + h * HD;
  const bf16* Kb = Kg + bS * HDIM + h * HD;
  const bf16* Vb = VTg + (size_t)bh * HD * S;
  const int* mrow = mask + bS;

  // gll source pointers (chunk 0), advanced per chunk
  const bf16 *ksrc[4], *vsrc[4];
#pragma unroll
  for (int it = 0; it < 4; ++it) {
    const int key = it * 16 + (tid >> 4);
    const int g = tid & 15;
    const int fk = (key ^ (key >> 3)) & 7;
    const int db = (g & 8) | ((g ^ fk) & 7);
    ksrc[it] = Kb + (size_t)key * HDIM + db * 8;
    const int d = it * 32 + (tid >> 3);
    const int kb = (tid & 7) ^ (d & 7);
    vsrc[it] = Vb + (size_t)d * S + kb * 8;
  }

  bf16x8 qf[2][4];
#pragma unroll
  for (int qt = 0; qt < 2; ++qt)
#pragma unroll
    for (int s = 0; s < 4; ++s)
      qf[qt][s] = *(const bf16x8*)(Qb + (size_t)(q0 + qt * 16 + l16) * HDIM + s * 32 + quad * 8);

  float lsum[2] = {0.f, 0.f};
  f32x4 o[2][8] = {};
  const float scale2 = 0.08838834764831845f * 1.4426950408889634f;
  const int nchunk = S / 64;

  for (int c0 = 0; c0 < nchunk; ++c0) {
    __syncthreads();   // previous compute done with Ks/Vt/biass
#pragma unroll
    for (int it = 0; it < 4; ++it) {
      gload_lds16(ksrc[it], Ks + it * 2048 + tid * 8);
      gload_lds16(vsrc[it], Vt + it * 2048 + tid * 8);
      ksrc[it] += 64 * HDIM;
      vsrc[it] += 64;
    }
    if (tid < 64) biass[tid] = mrow[c0 * 64 + tid] ? 0.f : -1e9f;
    __syncthreads();   // drains vmcnt -> tiles ready

    // ---- S^T = K Q^T ----
    f32x4 s4[2][4] = {};
#pragma unroll
    for (int g = 0; g < 4; ++g) {
      const int key = g * 16 + l16;
      const int fk = (key ^ (key >> 3)) & 7;
#pragma unroll
      for (int s = 0; s < 4; ++s) {
        const int db = s * 4 + quad;
        const int gr = (db & 8) | ((db ^ fk) & 7);
        bf16x8 kf = *(const bf16x8*)&Ks[key * 128 + gr * 8];
        s4[0][g] = mfma16(kf, qf[0][s], s4[0][g]);
        s4[1][g] = mfma16(kf, qf[1][s], s4[1][g]);
      }
    }
    // ---- softmax + packed transpose-write ----
#pragma unroll
    for (int qt = 0; qt < 2; ++qt) {
      const int base = (w * 2 + qt) * 1024;
#pragma unroll
      for (int g = 0; g < 4; ++g) {
        bf16x4 pk;
#pragma unroll
        for (int i = 0; i < 4; ++i) {
          const float pv = exp2f(fmaf(s4[qt][g][i], scale2, biass[g * 16 + quad * 4 + i]));
          lsum[qt] += pv;
          pk[i] = (bf16)pv;
        }
        const int sw = (2 * g + (quad >> 1)) ^ (l16 & 7);
        *(bf16x4*)&Ps[base + l16 * 64 + sw * 8 + (quad & 1) * 4] = pk;
      }
    }
    // ---- PV ----
#pragma unroll
    for (int kk = 0; kk < 2; ++kk) {
      const int kb = kk * 4 + quad;
      bf16x8 pf0 = *(const bf16x8*)&Ps[(w * 2) * 1024 + l16 * 64 + ((kb ^ (l16 & 7)) << 3)];
      bf16x8 pf1 = *(const bf16x8*)&Ps[(w * 2 + 1) * 1024 + l16 * 64 + ((kb ^ (l16 & 7)) << 3)];
#pragma unroll
      for (int dg = 0; dg < 8; ++dg) {
        const int d = dg * 16 + l16;
        bf16x8 vf = *(const bf16x8*)&Vt[d * 64 + ((kb ^ (d & 7)) << 3)];
        o[0][dg] = mfma16(pf0, vf, o[0][dg]);
        o[1][dg] = mfma16(pf1, vf, o[1][dg]);
      }
    }
  }

#pragma unroll
  for (int qt = 0; qt < 2; ++qt) {
    lsum[qt] += __shfl_xor(lsum[qt], 16);
    lsum[qt] += __shfl_xor(lsum[qt], 32);
  }
#pragma unroll
  for (int qt = 0; qt < 2; ++qt)
#pragma unroll
    for (int i = 0; i < 4; ++i) {
      const float ls = __shfl(lsum[qt], quad * 4 + i);
      const float inv = 1.0f / ls;
      const int row = q0 + qt * 16 + quad * 4 + i;
#pragma unroll
      for (int dg = 0; dg < 8; ++dg)
        ctx[(bS + row) * HDIM + h * HD + dg * 16 + l16] = (bf16)(o[qt][dg][i] * inv);
    }
}

// ---------------- fused meta: [x|ctx]@[w1a|W']^T +b1' -> LN -> ReLU -> GEMM2 -> out
__global__ __launch_bounds__(256) void k_meta12(
    const bf16* __restrict__ A1, const bf16* __restrict__ A2,
    const bf16* __restrict__ Bw1, const bf16* __restrict__ Wp,
    const float* __restrict__ b1p, const float* __restrict__ g1,
    const float* __restrict__ be1,
    const bf16* __restrict__ Bw2, const float* __restrict__ b2,
    const float* __restrict__ g2, const float* __restrict__ be2,
    const float* __restrict__ w3, const float* __restrict__ b3,
    const int* __restrict__ tok, const int* __restrict__ msk,
    const float* __restrict__ imp, float* __restrict__ out) {
  __shared__ char smem[44032];
  __shared__ float part_s[64][4];
  __shared__ float part_q[64][4];
  bf16 (*As)[40]  = (bf16(*)[40])smem;
  bf16 (*Bs)[40]  = (bf16(*)[40])(smem + 5120);
  bf16 (*h1s)[264] = (bf16(*)[264])smem;
  bf16 (*Bs2)[40] = (bf16(*)[40])(smem + 33792);
  const int tid = threadIdx.x;
  const int w = tid >> 6, lane = tid & 63;
  const int quad = lane >> 4, l16 = lane & 15;
  const int tm = blockIdx.x * 64;
  const int lr = tid >> 2, lc = (tid & 3) * 8;

  f32x4 acc[4][4] = {};
  for (int k0 = 0; k0 < 2048; k0 += 32) {
    const int kg = k0 + lc;
    const bf16* ap = (kg < 1024) ? (A1 + (size_t)(tm + lr) * 1024 + kg)
                                 : (A2 + (size_t)(tm + lr) * 1024 + (kg - 1024));
    *(bf16x8*)&As[lr][lc] = *(const bf16x8*)ap;
#pragma unroll
    for (int it = 0; it < 4; ++it) {
      const int row = lr + it * 64;
      const bf16* bp = (kg < 1024) ? (Bw1 + (size_t)row * 2048 + kg)
                                   : (Wp + (size_t)row * 1024 + (kg - 1024));
      *(bf16x8*)&Bs[row][lc] = *(const bf16x8*)bp;
    }
    __syncthreads();
    bf16x8 af[4], bfr[4];
#pragma unroll
    for (int mt = 0; mt < 4; ++mt) af[mt] = *(const bf16x8*)&As[mt * 16 + l16][quad * 8];
#pragma unroll
    for (int nt = 0; nt < 4; ++nt)
      bfr[nt] = *(const bf16x8*)&Bs[w * 64 + nt * 16 + l16][quad * 8];
#pragma unroll
    for (int mt = 0; mt < 4; ++mt)
#pragma unroll
      for (int nt = 0; nt < 4; ++nt)
        acc[mt][nt] = mfma16(af[mt], bfr[nt], acc[mt][nt]);
    __syncthreads();
  }

  float bv[4], gv[4], bev[4];
#pragma unroll
  for (int nt = 0; nt < 4; ++nt) {
    const int col = w * 64 + nt * 16 + l16;
    bv[nt] = b1p[col]; gv[nt] = g1[col]; bev[nt] = be1[col];
  }
#pragma unroll
  for (int mt = 0; mt < 4; ++mt)
#pragma unroll
    for (int i = 0; i < 4; ++i) {
      float s = 0.f, q = 0.f;
#pragma unroll
      for (int nt = 0; nt < 4; ++nt) {
        const float v = acc[mt][nt][i] + bv[nt];
        s += v; q += v * v;
      }
#pragma unroll
      for (int off = 1; off < 16; off <<= 1) { s += __shfl_xor(s, off); q += __shfl_xor(q, off); }
      if (l16 == 0) {
        const int row = mt * 16 + quad * 4 + i;
        part_s[row][w] = s; part_q[row][w] = q;
      }
    }
  __syncthreads();
#pragma unroll
  for (int mt = 0; mt < 4; ++mt)
#pragma unroll
    for (int i = 0; i < 4; ++i) {
      const int row = mt * 16 + quad * 4 + i;
      const float4 ps = *(const float4*)part_s[row];
      const float4 pq = *(const float4*)part_q[row];
      const float sum = ps.x + ps.y + ps.z + ps.w;
      const float sq = pq.x + pq.y + pq.z + pq.w;
      const float mean = sum / MD1;
      const float var = sq / MD1 - mean * mean;
      const float r = rsqrtf(var + LNEPS);
#pragma unroll
      for (int nt = 0; nt < 4; ++nt) {
        const int col = w * 64 + nt * 16 + l16;
        const float v = acc[mt][nt][i] + bv[nt];
        const float t = (v - mean) * r * gv[nt] + bev[nt];
        h1s[row][col] = (bf16)fmaxf(t, 0.f);
      }
    }
  __syncthreads();

  f32x4 acc2[8] = {};
  for (int k0 = 0; k0 < MD1; k0 += 32) {
    const int kg = k0 + lc;
#pragma unroll
    for (int it = 0; it < 2; ++it)
      *(bf16x8*)&Bs2[lr + it * 64][lc] =
          *(const bf16x8*)(Bw2 + (size_t)(lr + it * 64) * MD1 + kg);
    __syncthreads();
    bf16x8 af = *(const bf16x8*)&h1s[w * 16 + l16][k0 + quad * 8];
#pragma unroll
    for (int nt = 0; nt < 8; ++nt) {
      bf16x8 bfr = *(const bf16x8*)&Bs2[nt * 16 + l16][quad * 8];
      acc2[nt] = mfma16(af, bfr, acc2[nt]);
    }
    __syncthreads();
  }

  float bv2[8], gv2[8], bev2[8], w3v[8];
#pragma unroll
  for (int nt = 0; nt < 8; ++nt) {
    const int col = nt * 16 + l16;
    bv2[nt] = b2[col]; gv2[nt] = g2[col]; bev2[nt] = be2[col]; w3v[nt] = w3[col];
  }
  const float b3v = b3[0];
#pragma unroll
  for (int i = 0; i < 4; ++i) {
    float s = 0.f, q = 0.f;
#pragma unroll
    for (int nt = 0; nt < 8; ++nt) {
      const float v = acc2[nt][i] + bv2[nt];
      s += v; q += v * v;
    }
#pragma unroll
    for (int off = 1; off < 16; off <<= 1) { s += __shfl_xor(s, off); q += __shfl_xor(q, off); }
    const float mean = s / MD2;
    const float var = q / MD2 - mean * mean;
    const float r = rsqrtf(var + LNEPS);
    float d = 0.f;
#pragma unroll
    for (int nt = 0; nt < 8; ++nt) {
      const float v = acc2[nt][i] + bv2[nt];
      const float t = (v - mean) * r * gv2[nt] + bev2[nt];
      d += fmaxf(t, 0.f) * w3v[nt];
    }
#pragma unroll
    for (int off = 1; off < 16; off <<= 1) d += __shfl_xor(d, off);
    if (l16 == 0) {
      const int row = tm + w * 16 + quad * 4 + i;
      float wt = (d + b3v) * (1.f + imp[tok[row]]);
      wt = fminf(fmaxf(wt, 0.1f), 5.0f);
      out[row] = msk[row] ? wt : 0.f;
    }
  }
}

// ---------------- launch ----------------
extern "C" void kernel_launch(void* const* d_in, const int* in_sizes, int n_in,
                              void* d_out, int out_size, void* d_ws, size_t ws_size,
                              hipStream_t stream) {
  const float* hs  = (const float*)d_in[0];
  const int*   tok = (const int*)d_in[1];
  const int*   msk = (const int*)d_in[2];
  const float* pos = (const float*)d_in[3];
  const float* inw = (const float*)d_in[4];
  const float* inb = (const float*)d_in[5];
  const float* ow  = (const float*)d_in[6];
  const float* ob  = (const float*)d_in[7];
  const float* w1  = (const float*)d_in[8];
  const float* b1  = (const float*)d_in[9];
  const float* g1  = (const float*)d_in[10];
  const float* be1 = (const float*)d_in[11];
  const float* w2  = (const float*)d_in[12];
  const float* b2  = (const float*)d_in[13];
  const float* g2  = (const float*)d_in[14];
  const float* be2 = (const float*)d_in[15];
  const float* w3  = (const float*)d_in[16];
  const float* b3  = (const float*)d_in[17];
  const float* imp = (const float*)d_in[18];

  const int SH = in_sizes[3];
  const int S  = SH / HDIM;
  const int Bsz = in_sizes[0] / SH;
  const int M = Bsz * S;

  char* ws = (char*)d_ws;
  const size_t MB2 = (size_t)M * HDIM * 2;
  size_t off = 0;
  bf16* xbf = (bf16*)(ws + off);  off += MB2;
  bf16* Qb  = (bf16*)(ws + off);  off += MB2;
  bf16* Kb  = (bf16*)(ws + off);  off += MB2;
  bf16* VTb = (bf16*)(ws + off);  off += MB2;
  bf16* ctx = (bf16*)(ws + off);  off += MB2;
  bf16* winp = (bf16*)(ws + off); off += (size_t)3 * HDIM * HDIM * 2;
  bf16* w1b = (bf16*)(ws + off);  off += (size_t)MD1 * 2 * HDIM * 2;
  bf16* w2b = (bf16*)(ws + off);  off += (size_t)MD2 * MD1 * 2;
  bf16* Wp  = (bf16*)(ws + off);  off += (size_t)MD1 * HDIM * 2;
  float* b1p = (float*)(ws + off); off += (size_t)MD1 * 4;

  const int nprep = M * HDIM;
  const int n0 = 3 * HDIM * HDIM, n2 = MD1 * 2 * HDIM, n3 = MD2 * MD1;
  const int blocks_el = (nprep + n0 + n2 + n3) / 4 / 256;
  k_prep_all<<<blocks_el + 64 + MD1 / 64, 256, 0, stream>>>(
      hs, pos, xbf, SH, nprep, inw, winp, n0, w1, w1b, n2, w2, w2b, n3,
      ow, ob, b1, Wp, b1p, blocks_el);
  k_gemm_qkv<<<dim3(M / 128, (3 * HDIM) / 128), 256, 0, stream>>>(
      xbf, winp, inb, Qb, Kb, VTb, S, HDIM);
  k_flash<<<(S / 128) * Bsz * NHEADS, 256, 0, stream>>>(Qb, Kb, VTb, msk, ctx, S);
  k_meta12<<<M / 64, 256, 0, stream>>>(xbf, ctx, w1b, Wp, b1p, g1, be1,
                                       w2b, b2, g2, be2, w3, b3, tok, msk, imp,
                                       (float*)d_out);
}